// Round 3
// baseline (59.572 us; speedup 1.0000x reference)
//
#include <hip/hip_runtime.h>
#include <math.h>

#define NN 129
#define INC 129
#define OUTC 64
#define NE 4096
#define NW_A 16                 // waves per block, kernel A (1024 threads)
#define GRID_A 128
#define TOTW (GRID_A * NW_A)    // 2048 waves total

__device__ __forceinline__ float sigmf(float x) { return 1.0f / (1.0f + expf(-x)); }

// Kernel A: per-block redundant {score, perm} + grid-strided wave-per-element GRU -> W
__global__ __launch_bounds__(1024) void k_gruW(
    const float* __restrict__ x, const float* __restrict__ p,
    const float* __restrict__ W0,
    const float* __restrict__ w_ih, const float* __restrict__ w_hh,
    const float* __restrict__ b_ih, const float* __restrict__ b_hh,
    float* __restrict__ W)
{
    __shared__ float s_sc[NN];
    __shared__ int   s_perm[NN];
    __shared__ float s_rnorm;
    int t = threadIdx.x;
    int wv = t >> 6, lane = t & 63;

    // 1/||p|| (wave 0) — use precise sqrt, ranking must be stable
    if (wv == 0) {
        float a = 0.f;
        for (int c = lane; c < INC; c += 64) { float v = p[c]; a += v * v; }
        for (int off = 32; off; off >>= 1) a += __shfl_xor(a, off, 64);
        if (lane == 0) s_rnorm = 1.0f / sqrtf(a);
    }
    // raw dots: wave wv handles nodes wv, wv+16, ...
    for (int n = wv; n < NN; n += NW_A) {
        const float* xr = x + (size_t)n * INC;
        float a = 0.f;
        for (int c = lane; c < INC; c += 64) a += xr[c] * p[c];
        for (int off = 32; off; off >>= 1) a += __shfl_xor(a, off, 64);
        if (lane == 0) s_sc[n] = a;
    }
    __syncthreads();
    if (t < NN) s_sc[t] = tanhf(s_sc[t] * s_rnorm);
    __syncthreads();
    if (t < NN) {
        float my = s_sc[t];
        int rank = 0;
        for (int j = 0; j < NN; ++j) {
            float o = s_sc[j];
            rank += (o > my || (o == my && j < t)) ? 1 : 0;   // stable descending
        }
        s_perm[rank] = t;
    }
    __syncthreads();

    // GRU: one wave per output element (i,j), grid-strided
    int gw = blockIdx.x * NW_A + wv;
    for (int wid = gw; wid < NN * INC; wid += TOTW) {
        int i = wid / INC;
        int j = wid - i * INC;
        int pi = s_perm[i];
        float sc = s_sc[pi];
        const float* xr = x  + (size_t)pi * INC;
        const float* h0 = W0 + (size_t)i * INC;
        const float* wr = w_ih + (size_t)j * INC;
        const float* wz = wr + (size_t)INC * INC;
        const float* wn = wz + (size_t)INC * INC;
        const float* vr = w_hh + (size_t)j * INC;
        const float* vz = vr + (size_t)INC * INC;
        const float* vn = vz + (size_t)INC * INC;

        float sr = 0.f, szv = 0.f, an = 0.f, hn = 0.f;
        for (int c = lane; c < INC; c += 64) {
            float xv = xr[c] * sc;
            float hv = h0[c];
            sr  += xv * wr[c] + hv * vr[c];
            szv += xv * wz[c] + hv * vz[c];
            an  += xv * wn[c];
            hn  += hv * vn[c];
        }
        for (int off = 32; off; off >>= 1) {
            sr  += __shfl_xor(sr,  off, 64);
            szv += __shfl_xor(szv, off, 64);
            an  += __shfl_xor(an,  off, 64);
            hn  += __shfl_xor(hn,  off, 64);
        }
        if (lane == 0) {
            float r    = sigmf(sr  + b_ih[j]           + b_hh[j]);
            float z    = sigmf(szv + b_ih[INC + j]     + b_hh[INC + j]);
            float cand = tanhf(an + b_ih[2 * INC + j] + r * (hn + b_hh[2 * INC + j]));
            W[(size_t)i * INC + j] = (1.0f - z) * cand + z * h0[j];
        }
    }
}

// Kernel B: per output node c — local deg/dis, incoming-edge list, aggregate in
// feature space, (agg @ W) + bias, ELU, final linear. Exact by linearity:
// sum_e norm*(x[r]@W) == (sum_e norm*x[r]) @ W.
__global__ __launch_bounds__(256) void k_gcn_out(
    const float* __restrict__ x, const int* __restrict__ row,
    const int* __restrict__ col, const float* __restrict__ ew,
    const float* __restrict__ W, const float* __restrict__ cb,
    const float* __restrict__ lw, const float* __restrict__ lb,
    float* __restrict__ out)
{
    __shared__ float s_deg[NN];
    __shared__ float s_dis[NN];
    __shared__ int   s_lr[1024];
    __shared__ float s_lw[1024];
    __shared__ int   s_cnt;
    __shared__ float s_agg[NN];
    __shared__ float s_h[NN];
    int c = blockIdx.x, t = threadIdx.x;

    if (t < NN) s_deg[t] = 0.f;
    if (t == 0) s_cnt = 0;
    __syncthreads();
    for (int e = t; e < NE; e += 256) {
        int cc = col[e];
        float w = ew[e];
        atomicAdd(&s_deg[cc], w);
        if (cc == c) {
            int k = atomicAdd(&s_cnt, 1);
            if (k < 1024) { s_lr[k] = row[e]; s_lw[k] = w; }
        }
    }
    __syncthreads();
    if (t < NN) s_dis[t] = rsqrtf(fmaxf(s_deg[t] + 1.0f, 1e-12f));  // +1 self-loop
    __syncthreads();

    int cnt = min(s_cnt, 1024);
    float dc = s_dis[c];
    if (t < NN) {
        float a = dc * dc * x[(size_t)c * INC + t];        // self-loop term
        for (int k = 0; k < cnt; ++k) {
            int r = s_lr[k];
            float nrm = s_dis[r] * s_lw[k] * dc;
            a += nrm * x[(size_t)r * INC + t];
        }
        s_agg[t] = a;
    }
    __syncthreads();
    if (t < NN) {
        float g = cb[t];
        for (int cc2 = 0; cc2 < INC; ++cc2) g += s_agg[cc2] * W[(size_t)cc2 * INC + t];
        s_h[t] = (g > 0.f) ? g : expm1f(g);                // ELU
    }
    __syncthreads();
    int wv = t >> 6, lane = t & 63;
    for (int f = wv; f < OUTC; f += 4) {
        const float* wrow = lw + (size_t)f * INC;
        float a = 0.f;
        for (int cc2 = lane; cc2 < INC; cc2 += 64) a += s_h[cc2] * wrow[cc2];
        for (int off = 32; off; off >>= 1) a += __shfl_xor(a, off, 64);
        if (lane == 0) out[(size_t)c * OUTC + f] = a + lb[f];
    }
}

extern "C" void kernel_launch(void* const* d_in, const int* in_sizes, int n_in,
                              void* d_out, int out_size, void* d_ws, size_t ws_size,
                              hipStream_t stream)
{
    const float* x   = (const float*)d_in[0];
    const int*   ei  = (const int*)d_in[1];
    const float* ew  = (const float*)d_in[2];
    const float* pp  = (const float*)d_in[3];
    const float* W0  = (const float*)d_in[4];
    const float* wih = (const float*)d_in[5];
    const float* whh = (const float*)d_in[6];
    const float* bih = (const float*)d_in[7];
    const float* bhh = (const float*)d_in[8];
    const float* cb  = (const float*)d_in[9];
    const float* lw  = (const float*)d_in[10];
    const float* lb  = (const float*)d_in[11];
    float* out = (float*)d_out;

    float* W = (float*)d_ws;            // 129*129 f32

    const int* row = ei;                // edge_index[0]
    const int* col = ei + NE;           // edge_index[1]

    k_gruW<<<GRID_A, 1024, 0, stream>>>(x, pp, W0, wih, whh, bih, bhh, W);
    k_gcn_out<<<NN, 256, 0, stream>>>(x, row, col, ew, W, cb, lw, lb, out);
}